// Round 8
// baseline (677.994 us; speedup 1.0000x reference)
//
#include <hip/hip_runtime.h>

// ---------- bf16 helpers (bit-level, RNE) ----------
__device__ __forceinline__ float bf2f(unsigned short u) {
    union { unsigned int i; float f; } v;
    v.i = ((unsigned int)u) << 16;
    return v.f;
}
__device__ __forceinline__ unsigned short f2bf(float f) {
    union { float f; unsigned int u; } v;
    v.f = f;
    unsigned int u = v.u;
    u += 0x7FFFu + ((u >> 16) & 1u);   // round-to-nearest-even
    return (unsigned short)(u >> 16);
}
__device__ __forceinline__ unsigned int pack2bf(float lo, float hi) {
    return (unsigned int)f2bf(lo) | ((unsigned int)f2bf(hi) << 16);
}
__device__ __forceinline__ float loadElem(const void* p, size_t i, int isb) {
    return isb ? bf2f(((const unsigned short*)p)[i]) : ((const float*)p)[i];
}
__device__ __forceinline__ float bflo(unsigned int u) {
    union { unsigned int i; float f; } v; v.i = u << 16; return v.f;
}
__device__ __forceinline__ float bfhi(unsigned int u) {
    union { unsigned int i; float f; } v; v.i = u & 0xFFFF0000u; return v.f;
}

typedef __attribute__((ext_vector_type(8))) short bf16x8;   // MFMA A/B frag (4 VGPR)
typedef __attribute__((ext_vector_type(4))) float f32x4;    // MFMA C/D frag

#define CHUNK 4096            // edges per partition block (r7/r9/r11 proven)
#define BSHIFT 8              // 256 nodes per sort bucket (r7/r11 proven)

// ---------- per-block local dtype detect (replaces k_detect + flags) ----------
// Every block reads the SAME first words of ei/x (L2-broadcast) and derives
// q (int64 edges) and isb (bf16 x) redundantly. sh must have >=512 ints free.
__device__ __forceinline__ void detect_local(
        const int* ei, int nd, const unsigned int* xw, int nxw,
        int* sh, int& q, int& isb) {
    int t = threadIdx.x;
    int v = 0;
    for (int i = 1 + 2 * t; i < nd; i += 512) v |= ei[i];
    int pl = 0;
    for (int i = t; i < nxw; i += 256) {
        unsigned short lo = (unsigned short)(xw[i] & 0xFFFFu);
        float a = fabsf(bf2f(lo));
        if (a > 1e-5f && a < 100.0f) pl++;
    }
    sh[t] = v; sh[256 + t] = pl;
    __syncthreads();
    for (int off = 128; off > 0; off >>= 1) {
        if (t < off) { sh[t] |= sh[t + off]; sh[256 + t] += sh[256 + t + off]; }
        __syncthreads();
    }
    q   = (sh[0] == 0) ? 1 : 0;
    isb = (2 * sh[256] >= nxw) ? 1 : 0;
    __syncthreads();
}

// ---------- k_prep: bcount + cast + weight transpose + bias (one launch) ----------
// grid = nblk blocks x 256. Block b<nblk: LDS histogram of chunk b -> blockHist
// row b ([nblk][NBUK], coalesced). Blocks 0..2 additionally transpose weights.
// All blocks: grid-stride cast x -> xb.
__global__ __launch_bounds__(256) void k_prep(
        const int* __restrict__ ei, const void* __restrict__ x,
        int* __restrict__ blockHist, unsigned short* __restrict__ xb,
        const void* __restrict__ W1l, const void* __restrict__ W1r,
        const void* __restrict__ b1,
        const void* __restrict__ W2l, const void* __restrict__ W2r,
        const void* __restrict__ b2,
        unsigned short* __restrict__ wt1l, unsigned short* __restrict__ wt1r,
        unsigned short* __restrict__ wt2lr,
        float* __restrict__ bs1, float* __restrict__ bs2,
        int E, int NBUK, int nblk, int n8, int nd, int nxw) {
    __shared__ int sh[768];
    int t = threadIdx.x;
    int b = blockIdx.x;
    int q, isb;
    detect_local(ei, nd, (const unsigned int*)x, nxw, sh, q, isb);

    // ---- histogram of this block's edge chunk ----
    for (int i = t; i < NBUK; i += 256) sh[i] = 0;
    __syncthreads();
    int e0 = b * CHUNK, e1 = min(E, e0 + CHUNK);
    for (int e = e0 + t; e < e1; e += 256) {
        int dst = ei[((size_t)(E + e)) << q];
        atomicAdd(&sh[dst >> BSHIFT], 1);
    }
    __syncthreads();
    for (int i = t; i < NBUK; i += 256)
        blockHist[(size_t)b * NBUK + i] = sh[i];

    // ---- weight transposes + biases (blocks 0..2, rides with the above) ----
    if (b == 0) {
        for (int i = t; i < 64 * 64; i += 256) {
            int c = i >> 6, k = i & 63;
            wt1l[c * 72 + k] = isb ? ((const unsigned short*)W1l)[k * 64 + c]
                                   : f2bf(((const float*)W1l)[k * 64 + c]);
        }
    } else if (b == 1) {
        for (int i = t; i < 64 * 64; i += 256) {
            int c = i >> 6, k = i & 63;
            wt1r[c * 72 + k] = isb ? ((const unsigned short*)W1r)[k * 64 + c]
                                   : f2bf(((const float*)W1r)[k * 64 + c]);
        }
    } else if (b == 2) {
        for (int i = t; i < 32 * 64; i += 256) {
            int c = i >> 6, k = i & 63;
            wt2lr[c * 72 + k]        = isb ? ((const unsigned short*)W2l)[k * 32 + c]
                                           : f2bf(((const float*)W2l)[k * 32 + c]);
            wt2lr[(32 + c) * 72 + k] = isb ? ((const unsigned short*)W2r)[k * 32 + c]
                                           : f2bf(((const float*)W2r)[k * 32 + c]);
        }
        if (t < 64) bs1[t] = loadElem(b1, t, isb);
        if (t >= 64 && t < 96) bs2[t - 64] = loadElem(b2, t - 64, isb);
    }

    // ---- grid-stride cast x -> xb ----
    for (int i = b * 256 + t; i < n8; i += gridDim.x * 256) {
        if (isb) {
            ((uint4*)xb)[i] = ((const uint4*)x)[i];
        } else {
            const float4* xf = (const float4*)x;
            float4 p = xf[2 * i], r = xf[2 * i + 1];
            ushort4 lo = { f2bf(p.x), f2bf(p.y), f2bf(p.z), f2bf(p.w) };
            ushort4 hi = { f2bf(r.x), f2bf(r.y), f2bf(r.z), f2bf(r.w) };
            ((ushort4*)xb)[2 * i] = lo;
            ((ushort4*)xb)[2 * i + 1] = hi;
        }
    }
}

// ---------- k_scan: bucket totals + exclusive scan + cursor init (1 block) ----------
__global__ __launch_bounds__(512) void k_scan(
        const int* __restrict__ blockHist, int* __restrict__ bukOff,
        int* __restrict__ cur, int* __restrict__ rowptr,
        int NBUK, int nblk, int E, int N) {
    __shared__ int sh[512];
    int t = threadIdx.x;
    int tot = 0;
    if (t < NBUK)
        for (int b = 0; b < nblk; ++b)
            tot += blockHist[(size_t)b * NBUK + t];
    sh[t] = tot;
    __syncthreads();
    for (int off = 1; off < 512; off <<= 1) {
        int u = (t >= off) ? sh[t - off] : 0;
        __syncthreads();
        sh[t] += u;
        __syncthreads();
    }
    if (t < NBUK) {
        int excl = sh[t] - tot;
        bukOff[t] = excl;
        cur[t] = excl;
    }
    if (t == 0) { bukOff[NBUK] = E; rowptr[N] = E; }
}

// ---------- k_part: partition edges via global per-bucket atomic cursors ----------
__global__ __launch_bounds__(256) void k_part(
        const int* __restrict__ ei, int* __restrict__ cur,
        unsigned int* __restrict__ recs, int E, int nd) {
    __shared__ int sh[512];
    int t = threadIdx.x;
    int q, isb;
    detect_local(ei, nd, (const unsigned int*)ei, 0, sh, q, isb);  // isb unused
    int e0 = blockIdx.x * CHUNK, e1 = min(E, e0 + CHUNK);
    for (int e = e0 + t; e < e1; e += 256) {
        int dst = ei[((size_t)(E + e)) << q];
        int src = ei[((size_t)e) << q];
        int pos = atomicAdd(&cur[dst >> BSHIFT], 1);
        recs[pos] = ((unsigned int)src << BSHIFT) | (unsigned int)(dst & ((1 << BSHIFT) - 1));
    }
}

// ---------- k_csr: per-bucket CSR finalize (R6 verbatim) ----------
__global__ __launch_bounds__(256) void k_csr(
        const unsigned int* __restrict__ recs, const int* __restrict__ bukOff,
        int* __restrict__ rowptr, int* __restrict__ esorted, int N) {
    __shared__ int degLoc[256];
    __shared__ int offLoc[256];
    __shared__ int wcur[256];
    int t = threadIdx.x;
    int node0 = blockIdx.x << BSHIFT;
    int r0 = bukOff[blockIdx.x], r1 = bukOff[blockIdx.x + 1];
    degLoc[t] = 0;
    __syncthreads();
    for (int i = r0 + t; i < r1; i += 256)
        atomicAdd(&degLoc[recs[i] & 255], 1);
    __syncthreads();
    int v = degLoc[t];
    offLoc[t] = v;
    __syncthreads();
    for (int off = 1; off < 256; off <<= 1) {
        int u = (t >= off) ? offLoc[t - off] : 0;
        __syncthreads();
        offLoc[t] += u;
        __syncthreads();
    }
    int excl = offLoc[t] - v;
    int node = node0 + t;
    if (node < N) rowptr[node] = r0 + excl;
    wcur[t] = r0 + excl;
    __syncthreads();
    for (int i = r0 + t; i < r1; i += 256) {
        unsigned int rec = recs[i];
        int pos = atomicAdd(&wcur[rec & 255], 1);
        esorted[pos] = (int)(rec >> BSHIFT);
    }
}

// ---------- layer-1 fused kernel (R6 verbatim, proven 49 us) ----------
__global__ __launch_bounds__(256) void k_fused1(
        const unsigned short* __restrict__ feat,   // [N,64] bf16 (xb)
        const int* __restrict__ rowptr,
        const int* __restrict__ esorted,
        const unsigned short* __restrict__ wt1l,   // [64c][72] bf16 col-major
        const unsigned short* __restrict__ wt1r,
        const unsigned short* __restrict__ wt2lr,  // rows 0-31 W2l^T, 32-63 W2r^T
        const float* __restrict__ bs1,             // [64] f32
        const float* __restrict__ bs2,             // [32] f32
        unsigned short* __restrict__ zbuf,         // [N,32] bf16 = h@W2l
        unsigned short* __restrict__ gbuf,         // [N,32] bf16 = h@W2r + b2
        int N) {
    constexpr int SA2 = 72;                        // amB16 stride (144B, 2-way banks)
    constexpr int SW  = 72;                        // wT stride
    __shared__ __align__(16) unsigned short amB16[64 * SA2];
    __shared__ __align__(16) unsigned short wT[64 * SW];
    __shared__ float Bs[64];
    __shared__ float Bs2[32];

    int t = threadIdx.x;
    int node0 = blockIdx.x << 6;

    // stage wt1l (coalesced uint4 copy; pad shorts never read by MFMA frags)
    for (int i = t; i < 576; i += 256)
        ((uint4*)wT)[i] = ((const uint4*)wt1l)[i];
    if (t < 64) Bs[t] = bs1[t];
    if (t >= 64 && t < 96) Bs2[t - 64] = bs2[t - 64];

    // ---- phase 1: gather mean of neighbor rows -> amB16[nl][k] ----
    {
        int g = t >> 3, l = t & 7;                 // group 0..31, lane-in-group
        const unsigned short* fl = feat + 8 * l;   // lane channel offset
#pragma unroll
        for (int jj = 0; jj < 2; ++jj) {
            int nl = g + 32 * jj;
            int node = node0 + nl;
            float a0 = 0.f, a1 = 0.f, a2 = 0.f, a3 = 0.f;
            float a4 = 0.f, a5 = 0.f, a6 = 0.f, a7 = 0.f;
            float inv = 0.f;
            if (node < N) {
                int beg = rowptr[node], end = rowptr[node + 1];
                int d = end - beg;
                if (d > 0) {
                    inv = 1.0f / (float)d;
                    for (int bs = beg; bs < end; bs += 8) {
                        int cnt = min(end - bs, 8);
                        const int* ep = esorted + bs;
                        int dd = 0;
                        if (cnt == 8) {            // 8 rows in flight, imm offsets
                            int s0 = ep[0], s1 = ep[1], s2 = ep[2], s3 = ep[3];
                            int s4 = ep[4], s5 = ep[5], s6 = ep[6], s7 = ep[7];
                            uint4 u0 = *(const uint4*)(fl + (size_t)s0 * 64);
                            uint4 u1 = *(const uint4*)(fl + (size_t)s1 * 64);
                            uint4 u2 = *(const uint4*)(fl + (size_t)s2 * 64);
                            uint4 u3 = *(const uint4*)(fl + (size_t)s3 * 64);
                            uint4 u4 = *(const uint4*)(fl + (size_t)s4 * 64);
                            uint4 u5 = *(const uint4*)(fl + (size_t)s5 * 64);
                            uint4 u6 = *(const uint4*)(fl + (size_t)s6 * 64);
                            uint4 u7 = *(const uint4*)(fl + (size_t)s7 * 64);
                            a0 += bflo(u0.x) + bflo(u1.x) + bflo(u2.x) + bflo(u3.x)
                                + bflo(u4.x) + bflo(u5.x) + bflo(u6.x) + bflo(u7.x);
                            a1 += bfhi(u0.x) + bfhi(u1.x) + bfhi(u2.x) + bfhi(u3.x)
                                + bfhi(u4.x) + bfhi(u5.x) + bfhi(u6.x) + bfhi(u7.x);
                            a2 += bflo(u0.y) + bflo(u1.y) + bflo(u2.y) + bflo(u3.y)
                                + bflo(u4.y) + bflo(u5.y) + bflo(u6.y) + bflo(u7.y);
                            a3 += bfhi(u0.y) + bfhi(u1.y) + bfhi(u2.y) + bfhi(u3.y)
                                + bfhi(u4.y) + bfhi(u5.y) + bfhi(u6.y) + bfhi(u7.y);
                            a4 += bflo(u0.z) + bflo(u1.z) + bflo(u2.z) + bflo(u3.z)
                                + bflo(u4.z) + bflo(u5.z) + bflo(u6.z) + bflo(u7.z);
                            a5 += bfhi(u0.z) + bfhi(u1.z) + bfhi(u2.z) + bfhi(u3.z)
                                + bfhi(u4.z) + bfhi(u5.z) + bfhi(u6.z) + bfhi(u7.z);
                            a6 += bflo(u0.w) + bflo(u1.w) + bflo(u2.w) + bflo(u3.w)
                                + bflo(u4.w) + bflo(u5.w) + bflo(u6.w) + bflo(u7.w);
                            a7 += bfhi(u0.w) + bfhi(u1.w) + bfhi(u2.w) + bfhi(u3.w)
                                + bfhi(u4.w) + bfhi(u5.w) + bfhi(u6.w) + bfhi(u7.w);
                            dd = 8;
                        }
                        for (; dd + 4 <= cnt; dd += 4) {
                            int s0 = ep[dd + 0], s1 = ep[dd + 1];
                            int s2 = ep[dd + 2], s3 = ep[dd + 3];
                            uint4 u0 = *(const uint4*)(fl + (size_t)s0 * 64);
                            uint4 u1 = *(const uint4*)(fl + (size_t)s1 * 64);
                            uint4 u2 = *(const uint4*)(fl + (size_t)s2 * 64);
                            uint4 u3 = *(const uint4*)(fl + (size_t)s3 * 64);
                            a0 += bflo(u0.x) + bflo(u1.x) + bflo(u2.x) + bflo(u3.x);
                            a1 += bfhi(u0.x) + bfhi(u1.x) + bfhi(u2.x) + bfhi(u3.x);
                            a2 += bflo(u0.y) + bflo(u1.y) + bflo(u2.y) + bflo(u3.y);
                            a3 += bfhi(u0.y) + bfhi(u1.y) + bfhi(u2.y) + bfhi(u3.y);
                            a4 += bflo(u0.z) + bflo(u1.z) + bflo(u2.z) + bflo(u3.z);
                            a5 += bfhi(u0.z) + bfhi(u1.z) + bfhi(u2.z) + bfhi(u3.z);
                            a6 += bflo(u0.w) + bflo(u1.w) + bflo(u2.w) + bflo(u3.w);
                            a7 += bfhi(u0.w) + bfhi(u1.w) + bfhi(u2.w) + bfhi(u3.w);
                        }
                        for (; dd < cnt; ++dd) {
                            int s = ep[dd];
                            uint4 u = *(const uint4*)(fl + (size_t)s * 64);
                            a0 += bflo(u.x); a1 += bfhi(u.x);
                            a2 += bflo(u.y); a3 += bfhi(u.y);
                            a4 += bflo(u.z); a5 += bfhi(u.z);
                            a6 += bflo(u.w); a7 += bfhi(u.w);
                        }
                    }
                }
            }
            uint4 packed = make_uint4(pack2bf(a0 * inv, a1 * inv),
                                      pack2bf(a2 * inv, a3 * inv),
                                      pack2bf(a4 * inv, a5 * inv),
                                      pack2bf(a6 * inv, a7 * inv));
            *(uint4*)&amB16[nl * SA2 + 8 * l] = packed;
        }
    }
    __syncthreads();

    // ---- phase 2: acc = am @ W1l via MFMA ----
    // A lane: row=l&15, k=(l>>4)*8+j; B lane: col=l&15, same k; D: col=l&15, row=(l>>4)*4+r.
    int wid = t >> 6, lane = t & 63;
    int arow = lane & 15;
    int kgrp = (lane >> 4) * 8;
    f32x4 acc[4];
#pragma unroll
    for (int ct = 0; ct < 4; ++ct) acc[ct] = (f32x4){0.f, 0.f, 0.f, 0.f};

    const unsigned short* aBase = &amB16[(16 * wid + arow) * SA2 + kgrp];
#pragma unroll
    for (int kh = 0; kh < 2; ++kh) {
        bf16x8 a = *(const bf16x8*)(aBase + kh * 32);
#pragma unroll
        for (int ct = 0; ct < 4; ++ct) {
            bf16x8 bb = *(const bf16x8*)&wT[(16 * ct + arow) * SW + kh * 32 + kgrp];
            acc[ct] = __builtin_amdgcn_mfma_f32_16x16x32_bf16(a, bb, acc[ct], 0, 0, 0);
        }
    }
    __syncthreads();

    // ---- restage: own rows -> amB16 (uint4 copy), wt1r -> wT (uint4 copy) ----
    for (int i = t; i < 64 * 8; i += 256) {
        int nl = i >> 3, c = i & 7;
        int gn = node0 + nl;
        uint4 u = make_uint4(0u, 0u, 0u, 0u);
        if (gn < N) u = *(const uint4*)(feat + (size_t)gn * 64 + 8 * c);
        *(uint4*)&amB16[nl * SA2 + 8 * c] = u;
    }
    for (int i = t; i < 576; i += 256)
        ((uint4*)wT)[i] = ((const uint4*)wt1r)[i];
    __syncthreads();

    // ---- phase 3: acc += own @ W1r via MFMA ----
#pragma unroll
    for (int kh = 0; kh < 2; ++kh) {
        bf16x8 a = *(const bf16x8*)(aBase + kh * 32);
#pragma unroll
        for (int ct = 0; ct < 4; ++ct) {
            bf16x8 bb = *(const bf16x8*)&wT[(16 * ct + arow) * SW + kh * 32 + kgrp];
            acc[ct] = __builtin_amdgcn_mfma_f32_16x16x32_bf16(a, bb, acc[ct], 0, 0, 0);
        }
    }
    __syncthreads();   // all phase-3 LDS reads done before overwrite

    // ---- stage 4: h -> amB16 (bf16), wt2lr -> wT (uint4 copy) ----
    {
        int rbase = (lane >> 4) * 4;
#pragma unroll
        for (int ct = 0; ct < 4; ++ct) {
            int ch = 16 * ct + arow;
            float bv = Bs[ch];
#pragma unroll
            for (int r = 0; r < 4; ++r) {
                int nl = 16 * wid + rbase + r;
                float v = fmaxf(acc[ct][r] + bv, 0.f);       // relu(h)
                amB16[nl * SA2 + ch] = f2bf(v);
            }
        }
    }
    for (int i = t; i < 576; i += 256)
        ((uint4*)wT)[i] = ((const uint4*)wt2lr)[i];
    __syncthreads();

    // ---- stage 4 MFMAs: z = h@W2l, g = h@W2r ----
    f32x4 accz[2], accg[2];
#pragma unroll
    for (int ct = 0; ct < 2; ++ct) {
        accz[ct] = (f32x4){0.f, 0.f, 0.f, 0.f};
        accg[ct] = (f32x4){0.f, 0.f, 0.f, 0.f};
    }
#pragma unroll
    for (int kh = 0; kh < 2; ++kh) {
        bf16x8 a = *(const bf16x8*)(aBase + kh * 32);
#pragma unroll
        for (int ct = 0; ct < 2; ++ct) {
            bf16x8 bz = *(const bf16x8*)&wT[(16 * ct + arow) * SW + kh * 32 + kgrp];
            bf16x8 bg = *(const bf16x8*)&wT[(32 + 16 * ct + arow) * SW + kh * 32 + kgrp];
            accz[ct] = __builtin_amdgcn_mfma_f32_16x16x32_bf16(a, bz, accz[ct], 0, 0, 0);
            accg[ct] = __builtin_amdgcn_mfma_f32_16x16x32_bf16(a, bg, accg[ct], 0, 0, 0);
        }
    }

    // ---- epilogue: write z (bf16), g = h@W2r + b2 (bf16) ----
#pragma unroll
    for (int ct = 0; ct < 2; ++ct) {
        int ch = 16 * ct + arow;
        float b2v = Bs2[ch];
#pragma unroll
        for (int r = 0; r < 4; ++r) {
            int node = node0 + 16 * wid + (lane >> 4) * 4 + r;
            if (node >= N) continue;
            zbuf[(size_t)node * 32 + ch] = f2bf(accz[ct][r]);
            gbuf[(size_t)node * 32 + ch] = f2bf(accg[ct][r] + b2v);
        }
    }
}

// ---------- layer-2 kernel: out = mean_nbr(z) + g (R6 structure + local isb) ----------
__global__ __launch_bounds__(256) void k_final(
        const unsigned short* __restrict__ zbuf,   // [N,32] bf16
        const unsigned short* __restrict__ gbuf,   // [N,32] bf16 (includes b2)
        const int* __restrict__ rowptr,
        const int* __restrict__ esorted,
        void* __restrict__ outp,                   // [N,32] f32 (or bf16 if isb)
        int N, const void* __restrict__ x, int nxw) {
    __shared__ int shp[256];
    int t = threadIdx.x;
    int node0 = blockIdx.x << 6;

    // local isb detect from x (L2-broadcast 2KB)
    {
        const unsigned int* xw = (const unsigned int*)x;
        int pl = 0;
        for (int i = t; i < nxw; i += 256) {
            unsigned short lo = (unsigned short)(xw[i] & 0xFFFFu);
            float a = fabsf(bf2f(lo));
            if (a > 1e-5f && a < 100.0f) pl++;
        }
        shp[t] = pl;
        __syncthreads();
        for (int off = 128; off > 0; off >>= 1) {
            if (t < off) shp[t] += shp[t + off];
            __syncthreads();
        }
    }
    int isb = (2 * shp[0] >= nxw) ? 1 : 0;

    int g = t >> 3, l = t & 7;                     // group 0..31, lane-in-group
    const unsigned short* fl = zbuf + 4 * l;       // 4 channels per lane
#pragma unroll
    for (int jj = 0; jj < 2; ++jj) {
        int nl = g + 32 * jj;
        int node = node0 + nl;
        if (node >= N) continue;
        float a0 = 0.f, a1 = 0.f, a2 = 0.f, a3 = 0.f;
        float inv = 0.f;
        int beg = rowptr[node], end = rowptr[node + 1];
        int d = end - beg;
        if (d > 0) {
            inv = 1.0f / (float)d;
            for (int bs = beg; bs < end; bs += 8) {
                int cnt = min(end - bs, 8);
                const int* ep = esorted + bs;
                int dd = 0;
                if (cnt == 8) {                    // 8 rows in flight
                    int s0 = ep[0], s1 = ep[1], s2 = ep[2], s3 = ep[3];
                    int s4 = ep[4], s5 = ep[5], s6 = ep[6], s7 = ep[7];
                    uint2 u0 = *(const uint2*)(fl + (size_t)s0 * 32);
                    uint2 u1 = *(const uint2*)(fl + (size_t)s1 * 32);
                    uint2 u2 = *(const uint2*)(fl + (size_t)s2 * 32);
                    uint2 u3 = *(const uint2*)(fl + (size_t)s3 * 32);
                    uint2 u4 = *(const uint2*)(fl + (size_t)s4 * 32);
                    uint2 u5 = *(const uint2*)(fl + (size_t)s5 * 32);
                    uint2 u6 = *(const uint2*)(fl + (size_t)s6 * 32);
                    uint2 u7 = *(const uint2*)(fl + (size_t)s7 * 32);
                    a0 += bflo(u0.x) + bflo(u1.x) + bflo(u2.x) + bflo(u3.x)
                        + bflo(u4.x) + bflo(u5.x) + bflo(u6.x) + bflo(u7.x);
                    a1 += bfhi(u0.x) + bfhi(u1.x) + bfhi(u2.x) + bfhi(u3.x)
                        + bfhi(u4.x) + bfhi(u5.x) + bfhi(u6.x) + bfhi(u7.x);
                    a2 += bflo(u0.y) + bflo(u1.y) + bflo(u2.y) + bflo(u3.y)
                        + bflo(u4.y) + bflo(u5.y) + bflo(u6.y) + bflo(u7.y);
                    a3 += bfhi(u0.y) + bfhi(u1.y) + bfhi(u2.y) + bfhi(u3.y)
                        + bfhi(u4.y) + bfhi(u5.y) + bfhi(u6.y) + bfhi(u7.y);
                    dd = 8;
                }
                for (; dd + 4 <= cnt; dd += 4) {
                    int s0 = ep[dd + 0], s1 = ep[dd + 1];
                    int s2 = ep[dd + 2], s3 = ep[dd + 3];
                    uint2 u0 = *(const uint2*)(fl + (size_t)s0 * 32);
                    uint2 u1 = *(const uint2*)(fl + (size_t)s1 * 32);
                    uint2 u2 = *(const uint2*)(fl + (size_t)s2 * 32);
                    uint2 u3 = *(const uint2*)(fl + (size_t)s3 * 32);
                    a0 += bflo(u0.x) + bflo(u1.x) + bflo(u2.x) + bflo(u3.x);
                    a1 += bfhi(u0.x) + bfhi(u1.x) + bfhi(u2.x) + bfhi(u3.x);
                    a2 += bflo(u0.y) + bflo(u1.y) + bflo(u2.y) + bflo(u3.y);
                    a3 += bfhi(u0.y) + bfhi(u1.y) + bfhi(u2.y) + bfhi(u3.y);
                }
                for (; dd < cnt; ++dd) {
                    int s = ep[dd];
                    uint2 u = *(const uint2*)(fl + (size_t)s * 32);
                    a0 += bflo(u.x); a1 += bfhi(u.x);
                    a2 += bflo(u.y); a3 += bfhi(u.y);
                }
            }
        }
        uint2 gv = *(const uint2*)(gbuf + (size_t)node * 32 + 4 * l);
        float r0 = a0 * inv + bflo(gv.x);
        float r1 = a1 * inv + bfhi(gv.x);
        float r2 = a2 * inv + bflo(gv.y);
        float r3 = a3 * inv + bfhi(gv.y);
        if (!isb) {
            *(float4*)((float*)outp + (size_t)node * 32 + 4 * l) =
                make_float4(r0, r1, r2, r3);
        } else {
            ushort4 o = { f2bf(r0), f2bf(r1), f2bf(r2), f2bf(r3) };
            *(ushort4*)((unsigned short*)outp + (size_t)node * 32 + 4 * l) = o;
        }
    }
}

extern "C" void kernel_launch(void* const* d_in, const int* in_sizes, int n_in,
                              void* d_out, int out_size, void* d_ws, size_t ws_size,
                              hipStream_t stream) {
    const void* x   = d_in[0];
    const int*  ei  = (const int*)d_in[1];
    const void* W1l = d_in[2];
    const void* W1r = d_in[3];
    const void* b1  = d_in[4];
    const void* W2l = d_in[5];
    const void* W2r = d_in[6];
    const void* b2  = d_in[7];

    const int N = in_sizes[0] / 64;
    const int E = in_sizes[1] / 2;
    const int NBUK = (N + (1 << BSHIFT) - 1) >> BSHIFT;   // 391 @ N=100k (<= 512)
    const int nblk = (E + CHUNK - 1) / CHUNK;             // 293 @ E=1.2M

    // ws: bukOff | cur | rowptr[N+1] | recs[E] | esorted[E] | xb | h
    //     | wt1l | wt1r | wt2lr | bs1 | bs2 | blockHist[nblk][NBUK]
    char* base = (char*)d_ws;
    size_t off = 0;
    auto alloc = [&](size_t bytes) { size_t o = off; off = (off + bytes + 255) & ~(size_t)255; return o; };
    int* bukOff  = (int*)(base + alloc((size_t)(NBUK + 1) * 4));
    int* cur     = (int*)(base + alloc((size_t)(NBUK + 1) * 4));
    int* rowptr  = (int*)(base + alloc((size_t)(N + 1) * 4));
    unsigned int* recs = (unsigned int*)(base + alloc((size_t)E * 4));
    int* esorted = (int*)(base + alloc((size_t)E * 4));
    unsigned short* xb = (unsigned short*)(base + alloc((size_t)N * 64 * 2));
    unsigned short* h  = (unsigned short*)(base + alloc((size_t)N * 64 * 2));
    unsigned short* wt1l  = (unsigned short*)(base + alloc(64 * 72 * 2));
    unsigned short* wt1r  = (unsigned short*)(base + alloc(64 * 72 * 2));
    unsigned short* wt2lr = (unsigned short*)(base + alloc(64 * 72 * 2));
    float* bs1 = (float*)(base + alloc(64 * 4));
    float* bs2 = (float*)(base + alloc(32 * 4));
    int* blockHist = (int*)(base + alloc((size_t)nblk * NBUK * 4));
    (void)ws_size;

    unsigned short* zbuf = h;                       // [N,32] bf16
    unsigned short* gbuf = h + (size_t)N * 32;      // [N,32] bf16

    int nd = 2 * E; if (nd > 2048) nd = 2048;
    const int nxw = 512;

    // 1) bcount + cast + weight transpose + biases
    k_prep<<<nblk, 256, 0, stream>>>(ei, x, blockHist, xb,
                                     W1l, W1r, b1, W2l, W2r, b2,
                                     wt1l, wt1r, wt2lr, bs1, bs2,
                                     E, NBUK, nblk, N * 8, nd, nxw);
    // 2) bucket totals + exclusive scan + cursor init
    k_scan<<<1, 512, 0, stream>>>(blockHist, bukOff, cur, rowptr, NBUK, nblk, E, N);
    // 3) partition edges (global atomic cursors)
    k_part<<<nblk, 256, 0, stream>>>(ei, cur, recs, E, nd);
    // 4) per-bucket CSR finalize
    k_csr<<<NBUK, 256, 0, stream>>>(recs, bukOff, rowptr, esorted, N);

    const int ntile = (N + 63) / 64;
    // 5) layer 1 + pre-transform: z = relu_h@W2l, g = relu_h@W2r + b2
    k_fused1<<<ntile, 256, 0, stream>>>(xb, rowptr, esorted,
                                        wt1l, wt1r, wt2lr, bs1, bs2,
                                        zbuf, gbuf, N);
    // 6) layer 2: out = mean_nbr(z) + g
    k_final<<<ntile, 256, 0, stream>>>(zbuf, gbuf, rowptr, esorted, d_out, N, x, nxw);
}

// Round 9
// 206.180 us; speedup vs baseline: 3.2884x; 3.2884x over previous
//
#include <hip/hip_runtime.h>

// ---------- bf16 helpers (bit-level, RNE) ----------
__device__ __forceinline__ float bf2f(unsigned short u) {
    union { unsigned int i; float f; } v;
    v.i = ((unsigned int)u) << 16;
    return v.f;
}
__device__ __forceinline__ unsigned short f2bf(float f) {
    union { float f; unsigned int u; } v;
    v.f = f;
    unsigned int u = v.u;
    u += 0x7FFFu + ((u >> 16) & 1u);   // round-to-nearest-even
    return (unsigned short)(u >> 16);
}
__device__ __forceinline__ unsigned int pack2bf(float lo, float hi) {
    return (unsigned int)f2bf(lo) | ((unsigned int)f2bf(hi) << 16);
}
__device__ __forceinline__ float loadElem(const void* p, size_t i, int isb) {
    return isb ? bf2f(((const unsigned short*)p)[i]) : ((const float*)p)[i];
}
__device__ __forceinline__ float bflo(unsigned int u) {
    union { unsigned int i; float f; } v; v.i = u << 16; return v.f;
}
__device__ __forceinline__ float bfhi(unsigned int u) {
    union { unsigned int i; float f; } v; v.i = u & 0xFFFF0000u; return v.f;
}

typedef __attribute__((ext_vector_type(8))) short bf16x8;   // MFMA A/B frag (4 VGPR)
typedef __attribute__((ext_vector_type(4))) float f32x4;    // MFMA C/D frag

#define CHUNK 4096            // edges per partition block (r7/r9/r11 proven)
#define BSHIFT 8              // 256 nodes per sort bucket (r7/r11 proven)

// ---------- per-block local dtype detect ----------
// Every block reads the SAME first words of ei/x (L2-broadcast) and derives
// q (int64 edges) and isb (bf16 x) redundantly. sh must have >=512 ints free.
__device__ __forceinline__ void detect_local(
        const int* ei, int nd, const unsigned int* xw, int nxw,
        int* sh, int& q, int& isb) {
    int t = threadIdx.x;
    int v = 0;
    for (int i = 1 + 2 * t; i < nd; i += 512) v |= ei[i];
    int pl = 0;
    for (int i = t; i < nxw; i += 256) {
        unsigned short lo = (unsigned short)(xw[i] & 0xFFFFu);
        float a = fabsf(bf2f(lo));
        if (a > 1e-5f && a < 100.0f) pl++;
    }
    sh[t] = v; sh[256 + t] = pl;
    __syncthreads();
    for (int off = 128; off > 0; off >>= 1) {
        if (t < off) { sh[t] |= sh[t + off]; sh[256 + t] += sh[256 + t + off]; }
        __syncthreads();
    }
    q   = (sh[0] == 0) ? 1 : 0;
    isb = (2 * sh[256] >= nxw) ? 1 : 0;
    __syncthreads();
}

// ---------- k_prep: bcount + cast + weight transpose + bias (one launch) ----------
// grid = nblk blocks x 256. Block b: LDS histogram of edge chunk b -> blockHist
// BUCKET-MAJOR ([NBUK][nblk], as k_rowscan/k_part expect). Blocks 0..2 also
// transpose weights. All blocks: grid-stride cast x -> xb.
__global__ __launch_bounds__(256) void k_prep(
        const int* __restrict__ ei, const void* __restrict__ x,
        int* __restrict__ blockHist, unsigned short* __restrict__ xb,
        const void* __restrict__ W1l, const void* __restrict__ W1r,
        const void* __restrict__ b1,
        const void* __restrict__ W2l, const void* __restrict__ W2r,
        const void* __restrict__ b2,
        unsigned short* __restrict__ wt1l, unsigned short* __restrict__ wt1r,
        unsigned short* __restrict__ wt2lr,
        float* __restrict__ bs1, float* __restrict__ bs2,
        int E, int NBUK, int nblk, int n8, int nd, int nxw) {
    __shared__ int sh[768];
    int t = threadIdx.x;
    int b = blockIdx.x;
    int q, isb;
    detect_local(ei, nd, (const unsigned int*)x, nxw, sh, q, isb);

    // ---- histogram of this block's edge chunk ----
    for (int i = t; i < NBUK; i += 256) sh[i] = 0;
    __syncthreads();
    int e0 = b * CHUNK, e1 = min(E, e0 + CHUNK);
    for (int e = e0 + t; e < e1; e += 256) {
        int dst = ei[((size_t)(E + e)) << q];
        atomicAdd(&sh[dst >> BSHIFT], 1);
    }
    __syncthreads();
    for (int i = t; i < NBUK; i += 256)
        blockHist[(size_t)i * nblk + b] = sh[i];        // bucket-major (r11 layout)

    // ---- weight transposes + biases (blocks 0..2, rides with the above) ----
    if (b == 0) {
        for (int i = t; i < 64 * 64; i += 256) {
            int c = i >> 6, k = i & 63;
            wt1l[c * 72 + k] = isb ? ((const unsigned short*)W1l)[k * 64 + c]
                                   : f2bf(((const float*)W1l)[k * 64 + c]);
        }
    } else if (b == 1) {
        for (int i = t; i < 64 * 64; i += 256) {
            int c = i >> 6, k = i & 63;
            wt1r[c * 72 + k] = isb ? ((const unsigned short*)W1r)[k * 64 + c]
                                   : f2bf(((const float*)W1r)[k * 64 + c]);
        }
    } else if (b == 2) {
        for (int i = t; i < 32 * 64; i += 256) {
            int c = i >> 6, k = i & 63;
            wt2lr[c * 72 + k]        = isb ? ((const unsigned short*)W2l)[k * 32 + c]
                                           : f2bf(((const float*)W2l)[k * 32 + c]);
            wt2lr[(32 + c) * 72 + k] = isb ? ((const unsigned short*)W2r)[k * 32 + c]
                                           : f2bf(((const float*)W2r)[k * 32 + c]);
        }
        if (t < 64) bs1[t] = loadElem(b1, t, isb);
        if (t >= 64 && t < 96) bs2[t - 64] = loadElem(b2, t - 64, isb);
    }

    // ---- grid-stride cast x -> xb ----
    for (int i = b * 256 + t; i < n8; i += gridDim.x * 256) {
        if (isb) {
            ((uint4*)xb)[i] = ((const uint4*)x)[i];
        } else {
            const float4* xf = (const float4*)x;
            float4 p = xf[2 * i], r = xf[2 * i + 1];
            ushort4 lo = { f2bf(p.x), f2bf(p.y), f2bf(p.z), f2bf(p.w) };
            ushort4 hi = { f2bf(r.x), f2bf(r.y), f2bf(r.z), f2bf(r.w) };
            ((ushort4*)xb)[2 * i] = lo;
            ((ushort4*)xb)[2 * i + 1] = hi;
        }
    }
}

// ---------- k_rowscan: prefix-scan each bucket row across blocks (R6 verbatim) ----------
__global__ __launch_bounds__(256) void k_rowscan(
        int* __restrict__ blockHist, int* __restrict__ bukTot, int nblk) {
    __shared__ int sh[256];
    int t = threadIdx.x;
    int* row = blockHist + (size_t)blockIdx.x * nblk;
    int carry = 0;
    for (int base = 0; base < nblk; base += 256) {
        int i = base + t;
        int v = (i < nblk) ? row[i] : 0;
        sh[t] = v;
        __syncthreads();
        for (int off = 1; off < 256; off <<= 1) {
            int u = (t >= off) ? sh[t - off] : 0;
            __syncthreads();
            sh[t] += u;
            __syncthreads();
        }
        if (i < nblk) row[i] = carry + sh[t] - v;
        int tot = sh[255];
        __syncthreads();
        carry += tot;
    }
    if (t == 0) bukTot[blockIdx.x] = carry;
}

// ---------- k_toto: bucket-offset exclusive scan (1 block; R6 minus weights) ----------
__global__ __launch_bounds__(512) void k_toto(
        const int* __restrict__ bukTot, int* __restrict__ bukOff,
        int* __restrict__ rowptr, int NBUK, int E, int N) {
    __shared__ int sh[512];
    int t = threadIdx.x;
    int v = (t < NBUK) ? bukTot[t] : 0;
    sh[t] = v;
    __syncthreads();
    for (int off = 1; off < 512; off <<= 1) {
        int u = (t >= off) ? sh[t - off] : 0;
        __syncthreads();
        sh[t] += u;
        __syncthreads();
    }
    if (t < NBUK) bukOff[t] = sh[t] - v;
    if (t == 0) { bukOff[NBUK] = E; rowptr[N] = E; }
}

// ---------- k_part: partition edges via per-block LDS cursors (contention-free) ----------
__global__ __launch_bounds__(256) void k_part(
        const int* __restrict__ ei,
        const int* __restrict__ blockHist, const int* __restrict__ bukOff,
        unsigned int* __restrict__ recs, int E, int NBUK, int nblk, int nd) {
    __shared__ int sh[768];
    int t = threadIdx.x;
    int q, isb;
    detect_local(ei, nd, (const unsigned int*)ei, 0, sh, q, isb);   // isb unused
    for (int i = t; i < NBUK; i += 256)
        sh[i] = blockHist[(size_t)i * nblk + blockIdx.x] + bukOff[i];
    __syncthreads();
    int e0 = blockIdx.x * CHUNK, e1 = min(E, e0 + CHUNK);
    for (int e = e0 + t; e < e1; e += 256) {
        int dst = ei[((size_t)(E + e)) << q];
        int src = ei[((size_t)e) << q];
        int pos = atomicAdd(&sh[dst >> BSHIFT], 1);
        recs[pos] = ((unsigned int)src << BSHIFT) | (unsigned int)(dst & ((1 << BSHIFT) - 1));
    }
}

// ---------- k_csr: per-bucket CSR finalize (R6 verbatim) ----------
__global__ __launch_bounds__(256) void k_csr(
        const unsigned int* __restrict__ recs, const int* __restrict__ bukOff,
        int* __restrict__ rowptr, int* __restrict__ esorted, int N) {
    __shared__ int degLoc[256];
    __shared__ int offLoc[256];
    __shared__ int wcur[256];
    int t = threadIdx.x;
    int node0 = blockIdx.x << BSHIFT;
    int r0 = bukOff[blockIdx.x], r1 = bukOff[blockIdx.x + 1];
    degLoc[t] = 0;
    __syncthreads();
    for (int i = r0 + t; i < r1; i += 256)
        atomicAdd(&degLoc[recs[i] & 255], 1);
    __syncthreads();
    int v = degLoc[t];
    offLoc[t] = v;
    __syncthreads();
    for (int off = 1; off < 256; off <<= 1) {
        int u = (t >= off) ? offLoc[t - off] : 0;
        __syncthreads();
        offLoc[t] += u;
        __syncthreads();
    }
    int excl = offLoc[t] - v;
    int node = node0 + t;
    if (node < N) rowptr[node] = r0 + excl;
    wcur[t] = r0 + excl;
    __syncthreads();
    for (int i = r0 + t; i < r1; i += 256) {
        unsigned int rec = recs[i];
        int pos = atomicAdd(&wcur[rec & 255], 1);
        esorted[pos] = (int)(rec >> BSHIFT);
    }
}

// ---------- layer-1 fused kernel (R6 verbatim, proven 49 us) ----------
__global__ __launch_bounds__(256) void k_fused1(
        const unsigned short* __restrict__ feat,   // [N,64] bf16 (xb)
        const int* __restrict__ rowptr,
        const int* __restrict__ esorted,
        const unsigned short* __restrict__ wt1l,   // [64c][72] bf16 col-major
        const unsigned short* __restrict__ wt1r,
        const unsigned short* __restrict__ wt2lr,  // rows 0-31 W2l^T, 32-63 W2r^T
        const float* __restrict__ bs1,             // [64] f32
        const float* __restrict__ bs2,             // [32] f32
        unsigned short* __restrict__ zbuf,         // [N,32] bf16 = h@W2l
        unsigned short* __restrict__ gbuf,         // [N,32] bf16 = h@W2r + b2
        int N) {
    constexpr int SA2 = 72;                        // amB16 stride (144B, 2-way banks)
    constexpr int SW  = 72;                        // wT stride
    __shared__ __align__(16) unsigned short amB16[64 * SA2];
    __shared__ __align__(16) unsigned short wT[64 * SW];
    __shared__ float Bs[64];
    __shared__ float Bs2[32];

    int t = threadIdx.x;
    int node0 = blockIdx.x << 6;

    // stage wt1l (coalesced uint4 copy; pad shorts never read by MFMA frags)
    for (int i = t; i < 576; i += 256)
        ((uint4*)wT)[i] = ((const uint4*)wt1l)[i];
    if (t < 64) Bs[t] = bs1[t];
    if (t >= 64 && t < 96) Bs2[t - 64] = bs2[t - 64];

    // ---- phase 1: gather mean of neighbor rows -> amB16[nl][k] ----
    {
        int g = t >> 3, l = t & 7;                 // group 0..31, lane-in-group
        const unsigned short* fl = feat + 8 * l;   // lane channel offset
#pragma unroll
        for (int jj = 0; jj < 2; ++jj) {
            int nl = g + 32 * jj;
            int node = node0 + nl;
            float a0 = 0.f, a1 = 0.f, a2 = 0.f, a3 = 0.f;
            float a4 = 0.f, a5 = 0.f, a6 = 0.f, a7 = 0.f;
            float inv = 0.f;
            if (node < N) {
                int beg = rowptr[node], end = rowptr[node + 1];
                int d = end - beg;
                if (d > 0) {
                    inv = 1.0f / (float)d;
                    for (int bs = beg; bs < end; bs += 8) {
                        int cnt = min(end - bs, 8);
                        const int* ep = esorted + bs;
                        int dd = 0;
                        if (cnt == 8) {            // 8 rows in flight, imm offsets
                            int s0 = ep[0], s1 = ep[1], s2 = ep[2], s3 = ep[3];
                            int s4 = ep[4], s5 = ep[5], s6 = ep[6], s7 = ep[7];
                            uint4 u0 = *(const uint4*)(fl + (size_t)s0 * 64);
                            uint4 u1 = *(const uint4*)(fl + (size_t)s1 * 64);
                            uint4 u2 = *(const uint4*)(fl + (size_t)s2 * 64);
                            uint4 u3 = *(const uint4*)(fl + (size_t)s3 * 64);
                            uint4 u4 = *(const uint4*)(fl + (size_t)s4 * 64);
                            uint4 u5 = *(const uint4*)(fl + (size_t)s5 * 64);
                            uint4 u6 = *(const uint4*)(fl + (size_t)s6 * 64);
                            uint4 u7 = *(const uint4*)(fl + (size_t)s7 * 64);
                            a0 += bflo(u0.x) + bflo(u1.x) + bflo(u2.x) + bflo(u3.x)
                                + bflo(u4.x) + bflo(u5.x) + bflo(u6.x) + bflo(u7.x);
                            a1 += bfhi(u0.x) + bfhi(u1.x) + bfhi(u2.x) + bfhi(u3.x)
                                + bfhi(u4.x) + bfhi(u5.x) + bfhi(u6.x) + bfhi(u7.x);
                            a2 += bflo(u0.y) + bflo(u1.y) + bflo(u2.y) + bflo(u3.y)
                                + bflo(u4.y) + bflo(u5.y) + bflo(u6.y) + bflo(u7.y);
                            a3 += bfhi(u0.y) + bfhi(u1.y) + bfhi(u2.y) + bfhi(u3.y)
                                + bfhi(u4.y) + bfhi(u5.y) + bfhi(u6.y) + bfhi(u7.y);
                            a4 += bflo(u0.z) + bflo(u1.z) + bflo(u2.z) + bflo(u3.z)
                                + bflo(u4.z) + bflo(u5.z) + bflo(u6.z) + bflo(u7.z);
                            a5 += bfhi(u0.z) + bfhi(u1.z) + bfhi(u2.z) + bfhi(u3.z)
                                + bfhi(u4.z) + bfhi(u5.z) + bfhi(u6.z) + bfhi(u7.z);
                            a6 += bflo(u0.w) + bflo(u1.w) + bflo(u2.w) + bflo(u3.w)
                                + bflo(u4.w) + bflo(u5.w) + bflo(u6.w) + bflo(u7.w);
                            a7 += bfhi(u0.w) + bfhi(u1.w) + bfhi(u2.w) + bfhi(u3.w)
                                + bfhi(u4.w) + bfhi(u5.w) + bfhi(u6.w) + bfhi(u7.w);
                            dd = 8;
                        }
                        for (; dd + 4 <= cnt; dd += 4) {
                            int s0 = ep[dd + 0], s1 = ep[dd + 1];
                            int s2 = ep[dd + 2], s3 = ep[dd + 3];
                            uint4 u0 = *(const uint4*)(fl + (size_t)s0 * 64);
                            uint4 u1 = *(const uint4*)(fl + (size_t)s1 * 64);
                            uint4 u2 = *(const uint4*)(fl + (size_t)s2 * 64);
                            uint4 u3 = *(const uint4*)(fl + (size_t)s3 * 64);
                            a0 += bflo(u0.x) + bflo(u1.x) + bflo(u2.x) + bflo(u3.x);
                            a1 += bfhi(u0.x) + bfhi(u1.x) + bfhi(u2.x) + bfhi(u3.x);
                            a2 += bflo(u0.y) + bflo(u1.y) + bflo(u2.y) + bflo(u3.y);
                            a3 += bfhi(u0.y) + bfhi(u1.y) + bfhi(u2.y) + bfhi(u3.y);
                            a4 += bflo(u0.z) + bflo(u1.z) + bflo(u2.z) + bflo(u3.z);
                            a5 += bfhi(u0.z) + bfhi(u1.z) + bfhi(u2.z) + bfhi(u3.z);
                            a6 += bflo(u0.w) + bflo(u1.w) + bflo(u2.w) + bflo(u3.w);
                            a7 += bfhi(u0.w) + bfhi(u1.w) + bfhi(u2.w) + bfhi(u3.w);
                        }
                        for (; dd < cnt; ++dd) {
                            int s = ep[dd];
                            uint4 u = *(const uint4*)(fl + (size_t)s * 64);
                            a0 += bflo(u.x); a1 += bfhi(u.x);
                            a2 += bflo(u.y); a3 += bfhi(u.y);
                            a4 += bflo(u.z); a5 += bfhi(u.z);
                            a6 += bflo(u.w); a7 += bfhi(u.w);
                        }
                    }
                }
            }
            uint4 packed = make_uint4(pack2bf(a0 * inv, a1 * inv),
                                      pack2bf(a2 * inv, a3 * inv),
                                      pack2bf(a4 * inv, a5 * inv),
                                      pack2bf(a6 * inv, a7 * inv));
            *(uint4*)&amB16[nl * SA2 + 8 * l] = packed;
        }
    }
    __syncthreads();

    // ---- phase 2: acc = am @ W1l via MFMA ----
    // A lane: row=l&15, k=(l>>4)*8+j; B lane: col=l&15, same k; D: col=l&15, row=(l>>4)*4+r.
    int wid = t >> 6, lane = t & 63;
    int arow = lane & 15;
    int kgrp = (lane >> 4) * 8;
    f32x4 acc[4];
#pragma unroll
    for (int ct = 0; ct < 4; ++ct) acc[ct] = (f32x4){0.f, 0.f, 0.f, 0.f};

    const unsigned short* aBase = &amB16[(16 * wid + arow) * SA2 + kgrp];
#pragma unroll
    for (int kh = 0; kh < 2; ++kh) {
        bf16x8 a = *(const bf16x8*)(aBase + kh * 32);
#pragma unroll
        for (int ct = 0; ct < 4; ++ct) {
            bf16x8 bb = *(const bf16x8*)&wT[(16 * ct + arow) * SW + kh * 32 + kgrp];
            acc[ct] = __builtin_amdgcn_mfma_f32_16x16x32_bf16(a, bb, acc[ct], 0, 0, 0);
        }
    }
    __syncthreads();

    // ---- restage: own rows -> amB16 (uint4 copy), wt1r -> wT (uint4 copy) ----
    for (int i = t; i < 64 * 8; i += 256) {
        int nl = i >> 3, c = i & 7;
        int gn = node0 + nl;
        uint4 u = make_uint4(0u, 0u, 0u, 0u);
        if (gn < N) u = *(const uint4*)(feat + (size_t)gn * 64 + 8 * c);
        *(uint4*)&amB16[nl * SA2 + 8 * c] = u;
    }
    for (int i = t; i < 576; i += 256)
        ((uint4*)wT)[i] = ((const uint4*)wt1r)[i];
    __syncthreads();

    // ---- phase 3: acc += own @ W1r via MFMA ----
#pragma unroll
    for (int kh = 0; kh < 2; ++kh) {
        bf16x8 a = *(const bf16x8*)(aBase + kh * 32);
#pragma unroll
        for (int ct = 0; ct < 4; ++ct) {
            bf16x8 bb = *(const bf16x8*)&wT[(16 * ct + arow) * SW + kh * 32 + kgrp];
            acc[ct] = __builtin_amdgcn_mfma_f32_16x16x32_bf16(a, bb, acc[ct], 0, 0, 0);
        }
    }
    __syncthreads();   // all phase-3 LDS reads done before overwrite

    // ---- stage 4: h -> amB16 (bf16), wt2lr -> wT (uint4 copy) ----
    {
        int rbase = (lane >> 4) * 4;
#pragma unroll
        for (int ct = 0; ct < 4; ++ct) {
            int ch = 16 * ct + arow;
            float bv = Bs[ch];
#pragma unroll
            for (int r = 0; r < 4; ++r) {
                int nl = 16 * wid + rbase + r;
                float v = fmaxf(acc[ct][r] + bv, 0.f);       // relu(h)
                amB16[nl * SA2 + ch] = f2bf(v);
            }
        }
    }
    for (int i = t; i < 576; i += 256)
        ((uint4*)wT)[i] = ((const uint4*)wt2lr)[i];
    __syncthreads();

    // ---- stage 4 MFMAs: z = h@W2l, g = h@W2r ----
    f32x4 accz[2], accg[2];
#pragma unroll
    for (int ct = 0; ct < 2; ++ct) {
        accz[ct] = (f32x4){0.f, 0.f, 0.f, 0.f};
        accg[ct] = (f32x4){0.f, 0.f, 0.f, 0.f};
    }
#pragma unroll
    for (int kh = 0; kh < 2; ++kh) {
        bf16x8 a = *(const bf16x8*)(aBase + kh * 32);
#pragma unroll
        for (int ct = 0; ct < 2; ++ct) {
            bf16x8 bz = *(const bf16x8*)&wT[(16 * ct + arow) * SW + kh * 32 + kgrp];
            bf16x8 bg = *(const bf16x8*)&wT[(32 + 16 * ct + arow) * SW + kh * 32 + kgrp];
            accz[ct] = __builtin_amdgcn_mfma_f32_16x16x32_bf16(a, bz, accz[ct], 0, 0, 0);
            accg[ct] = __builtin_amdgcn_mfma_f32_16x16x32_bf16(a, bg, accg[ct], 0, 0, 0);
        }
    }

    // ---- epilogue: write z (bf16), g = h@W2r + b2 (bf16) ----
#pragma unroll
    for (int ct = 0; ct < 2; ++ct) {
        int ch = 16 * ct + arow;
        float b2v = Bs2[ch];
#pragma unroll
        for (int r = 0; r < 4; ++r) {
            int node = node0 + 16 * wid + (lane >> 4) * 4 + r;
            if (node >= N) continue;
            zbuf[(size_t)node * 32 + ch] = f2bf(accz[ct][r]);
            gbuf[(size_t)node * 32 + ch] = f2bf(accg[ct][r] + b2v);
        }
    }
}

// ---------- layer-2 kernel: out = mean_nbr(z) + g (R8 version, passed) ----------
__global__ __launch_bounds__(256) void k_final(
        const unsigned short* __restrict__ zbuf,   // [N,32] bf16
        const unsigned short* __restrict__ gbuf,   // [N,32] bf16 (includes b2)
        const int* __restrict__ rowptr,
        const int* __restrict__ esorted,
        void* __restrict__ outp,                   // [N,32] f32 (or bf16 if isb)
        int N, const void* __restrict__ x, int nxw) {
    __shared__ int shp[256];
    int t = threadIdx.x;
    int node0 = blockIdx.x << 6;

    // local isb detect from x (L2-broadcast 2KB)
    {
        const unsigned int* xw = (const unsigned int*)x;
        int pl = 0;
        for (int i = t; i < nxw; i += 256) {
            unsigned short lo = (unsigned short)(xw[i] & 0xFFFFu);
            float a = fabsf(bf2f(lo));
            if (a > 1e-5f && a < 100.0f) pl++;
        }
        shp[t] = pl;
        __syncthreads();
        for (int off = 128; off > 0; off >>= 1) {
            if (t < off) shp[t] += shp[t + off];
            __syncthreads();
        }
    }
    int isb = (2 * shp[0] >= nxw) ? 1 : 0;

    int g = t >> 3, l = t & 7;                     // group 0..31, lane-in-group
    const unsigned short* fl = zbuf + 4 * l;       // 4 channels per lane
#pragma unroll
    for (int jj = 0; jj < 2; ++jj) {
        int nl = g + 32 * jj;
        int node = node0 + nl;
        if (node >= N) continue;
        float a0 = 0.f, a1 = 0.f, a2 = 0.f, a3 = 0.f;
        float inv = 0.f;
        int beg = rowptr[node], end = rowptr[node + 1];
        int d = end - beg;
        if (d > 0) {
            inv = 1.0f / (float)d;
            for (int bs = beg; bs < end; bs += 8) {
                int cnt = min(end - bs, 8);
                const int* ep = esorted + bs;
                int dd = 0;
                if (cnt == 8) {                    // 8 rows in flight
                    int s0 = ep[0], s1 = ep[1], s2 = ep[2], s3 = ep[3];
                    int s4 = ep[4], s5 = ep[5], s6 = ep[6], s7 = ep[7];
                    uint2 u0 = *(const uint2*)(fl + (size_t)s0 * 32);
                    uint2 u1 = *(const uint2*)(fl + (size_t)s1 * 32);
                    uint2 u2 = *(const uint2*)(fl + (size_t)s2 * 32);
                    uint2 u3 = *(const uint2*)(fl + (size_t)s3 * 32);
                    uint2 u4 = *(const uint2*)(fl + (size_t)s4 * 32);
                    uint2 u5 = *(const uint2*)(fl + (size_t)s5 * 32);
                    uint2 u6 = *(const uint2*)(fl + (size_t)s6 * 32);
                    uint2 u7 = *(const uint2*)(fl + (size_t)s7 * 32);
                    a0 += bflo(u0.x) + bflo(u1.x) + bflo(u2.x) + bflo(u3.x)
                        + bflo(u4.x) + bflo(u5.x) + bflo(u6.x) + bflo(u7.x);
                    a1 += bfhi(u0.x) + bfhi(u1.x) + bfhi(u2.x) + bfhi(u3.x)
                        + bfhi(u4.x) + bfhi(u5.x) + bfhi(u6.x) + bfhi(u7.x);
                    a2 += bflo(u0.y) + bflo(u1.y) + bflo(u2.y) + bflo(u3.y)
                        + bflo(u4.y) + bflo(u5.y) + bflo(u6.y) + bflo(u7.y);
                    a3 += bfhi(u0.y) + bfhi(u1.y) + bfhi(u2.y) + bfhi(u3.y)
                        + bfhi(u4.y) + bfhi(u5.y) + bfhi(u6.y) + bfhi(u7.y);
                    dd = 8;
                }
                for (; dd + 4 <= cnt; dd += 4) {
                    int s0 = ep[dd + 0], s1 = ep[dd + 1];
                    int s2 = ep[dd + 2], s3 = ep[dd + 3];
                    uint2 u0 = *(const uint2*)(fl + (size_t)s0 * 32);
                    uint2 u1 = *(const uint2*)(fl + (size_t)s1 * 32);
                    uint2 u2 = *(const uint2*)(fl + (size_t)s2 * 32);
                    uint2 u3 = *(const uint2*)(fl + (size_t)s3 * 32);
                    a0 += bflo(u0.x) + bflo(u1.x) + bflo(u2.x) + bflo(u3.x);
                    a1 += bfhi(u0.x) + bfhi(u1.x) + bfhi(u2.x) + bfhi(u3.x);
                    a2 += bflo(u0.y) + bflo(u1.y) + bflo(u2.y) + bflo(u3.y);
                    a3 += bfhi(u0.y) + bfhi(u1.y) + bfhi(u2.y) + bfhi(u3.y);
                }
                for (; dd < cnt; ++dd) {
                    int s = ep[dd];
                    uint2 u = *(const uint2*)(fl + (size_t)s * 32);
                    a0 += bflo(u.x); a1 += bfhi(u.x);
                    a2 += bflo(u.y); a3 += bfhi(u.y);
                }
            }
        }
        uint2 gv = *(const uint2*)(gbuf + (size_t)node * 32 + 4 * l);
        float r0 = a0 * inv + bflo(gv.x);
        float r1 = a1 * inv + bfhi(gv.x);
        float r2 = a2 * inv + bflo(gv.y);
        float r3 = a3 * inv + bfhi(gv.y);
        if (!isb) {
            *(float4*)((float*)outp + (size_t)node * 32 + 4 * l) =
                make_float4(r0, r1, r2, r3);
        } else {
            ushort4 o = { f2bf(r0), f2bf(r1), f2bf(r2), f2bf(r3) };
            *(ushort4*)((unsigned short*)outp + (size_t)node * 32 + 4 * l) = o;
        }
    }
}

extern "C" void kernel_launch(void* const* d_in, const int* in_sizes, int n_in,
                              void* d_out, int out_size, void* d_ws, size_t ws_size,
                              hipStream_t stream) {
    const void* x   = d_in[0];
    const int*  ei  = (const int*)d_in[1];
    const void* W1l = d_in[2];
    const void* W1r = d_in[3];
    const void* b1  = d_in[4];
    const void* W2l = d_in[5];
    const void* W2r = d_in[6];
    const void* b2  = d_in[7];

    const int N = in_sizes[0] / 64;
    const int E = in_sizes[1] / 2;
    const int NBUK = (N + (1 << BSHIFT) - 1) >> BSHIFT;   // 391 @ N=100k (<= 512)
    const int nblk = (E + CHUNK - 1) / CHUNK;             // 293 @ E=1.2M

    // ws: bukTot | bukOff | rowptr[N+1] | recs[E] | esorted[E] | xb | h
    //     | wt1l | wt1r | wt2lr | bs1 | bs2 | blockHist[NBUK][nblk]
    char* base = (char*)d_ws;
    size_t off = 0;
    auto alloc = [&](size_t bytes) { size_t o = off; off = (off + bytes + 255) & ~(size_t)255; return o; };
    int* bukTot  = (int*)(base + alloc((size_t)NBUK * 4));
    int* bukOff  = (int*)(base + alloc((size_t)(NBUK + 1) * 4));
    int* rowptr  = (int*)(base + alloc((size_t)(N + 1) * 4));
    unsigned int* recs = (unsigned int*)(base + alloc((size_t)E * 4));
    int* esorted = (int*)(base + alloc((size_t)E * 4));
    unsigned short* xb = (unsigned short*)(base + alloc((size_t)N * 64 * 2));
    unsigned short* h  = (unsigned short*)(base + alloc((size_t)N * 64 * 2));
    unsigned short* wt1l  = (unsigned short*)(base + alloc(64 * 72 * 2));
    unsigned short* wt1r  = (unsigned short*)(base + alloc(64 * 72 * 2));
    unsigned short* wt2lr = (unsigned short*)(base + alloc(64 * 72 * 2));
    float* bs1 = (float*)(base + alloc(64 * 4));
    float* bs2 = (float*)(base + alloc(32 * 4));
    int* blockHist = (int*)(base + alloc((size_t)NBUK * nblk * 4));
    (void)ws_size;

    unsigned short* zbuf = h;                       // [N,32] bf16
    unsigned short* gbuf = h + (size_t)N * 32;      // [N,32] bf16

    int nd = 2 * E; if (nd > 2048) nd = 2048;
    const int nxw = 512;

    // 1) bcount (bucket-major) + cast + weight transpose + biases
    k_prep<<<nblk, 256, 0, stream>>>(ei, x, blockHist, xb,
                                     W1l, W1r, b1, W2l, W2r, b2,
                                     wt1l, wt1r, wt2lr, bs1, bs2,
                                     E, NBUK, nblk, N * 8, nd, nxw);
    // 2) per-bucket prefix scan across blocks
    k_rowscan<<<NBUK, 256, 0, stream>>>(blockHist, bukTot, nblk);
    // 3) bucket-offset exclusive scan
    k_toto<<<1, 512, 0, stream>>>(bukTot, bukOff, rowptr, NBUK, E, N);
    // 4) partition edges (per-block LDS cursors — contention-free)
    k_part<<<nblk, 256, 0, stream>>>(ei, blockHist, bukOff, recs, E, NBUK, nblk, nd);
    // 5) per-bucket CSR finalize
    k_csr<<<NBUK, 256, 0, stream>>>(recs, bukOff, rowptr, esorted, N);

    const int ntile = (N + 63) / 64;
    // 6) layer 1 + pre-transform: z = relu_h@W2l, g = relu_h@W2r + b2
    k_fused1<<<ntile, 256, 0, stream>>>(xb, rowptr, esorted,
                                        wt1l, wt1r, wt2lr, bs1, bs2,
                                        zbuf, gbuf, N);
    // 7) layer 2: out = mean_nbr(z) + g
    k_final<<<ntile, 256, 0, stream>>>(zbuf, gbuf, rowptr, esorted, d_out, N, x, nxw);
}